// Round 7
// baseline (138.321 us; speedup 1.0000x reference)
//
#include <hip/hip_runtime.h>
#include <hip/hip_bf16.h>
#include <hip/hip_fp8.h>
#include <math.h>

#define BROWS 4096
#define DIM   512
#define YEMB_B 2097152   // 4096*512 bytes, offset of emb rows in Yq (fp8)
#define TSTRIDE 191      // tile stride (tiles are 192 wide, overlap by 1)
#define NT 22            // tiles per dim; triangle tiles = 22*23/2 = 253

typedef float f32x4 __attribute__((ext_vector_type(4)));

// ---------------------------------------------------------------------------
// prep4: wave-per-row, no barriers. 8192 rows (low then emb), 4 rows/block.
// L2-normalize -> fp8 e4m3 row in Yq; s=sum(y^2), r=sum(y) from f32 y.
// (verified R12-R21: absmax 0.0)
// ---------------------------------------------------------------------------
__global__ __launch_bounds__(256) void prep4_kernel(
    const float* __restrict__ low, const float* __restrict__ emb,
    unsigned char* __restrict__ Yq,
    float* __restrict__ s_l, float* __restrict__ r_l,
    float* __restrict__ s_e, float* __restrict__ r_e,
    float* __restrict__ out) {
  const int tid = threadIdx.x;
  const int lane = tid & 63, wid = tid >> 6;
  const int rid = blockIdx.x * 4 + wid;          // 0..8191
  if (blockIdx.x == 0 && tid == 0) out[0] = 0.f;

  const bool is_low = (rid < BROWS);
  const int row = is_low ? rid : rid - BROWS;
  const float* x = (is_low ? low : emb) + (size_t)row * DIM;

  const float4 v0 = ((const float4*)x)[lane * 2];
  const float4 v1 = ((const float4*)x)[lane * 2 + 1];

  float ss = v0.x * v0.x + v0.y * v0.y + v0.z * v0.z + v0.w * v0.w +
             v1.x * v1.x + v1.y * v1.y + v1.z * v1.z + v1.w * v1.w;
#pragma unroll
  for (int o = 1; o < 64; o <<= 1) ss += __shfl_xor(ss, o, 64);
  const float inv = 1.0f / fmaxf(sqrtf(ss), 1e-12f);

  float y[8] = {v0.x * inv, v0.y * inv, v0.z * inv, v0.w * inv,
                v1.x * inv, v1.y * inv, v1.z * inv, v1.w * inv};

  union { unsigned char b[8]; unsigned long long u; } pk;
  float sv = 0.f, rv = 0.f;
#pragma unroll
  for (int i = 0; i < 8; ++i) {
    pk.b[i] = __hip_fp8_e4m3(y[i]).__x;   // OCP e4m3fn, HW RNE
    sv += y[i] * y[i];
    rv += y[i];
  }
  ((unsigned long long*)(Yq + (size_t)rid * 512))[lane] = pk.u;

#pragma unroll
  for (int o = 1; o < 64; o <<= 1) {
    sv += __shfl_xor(sv, o, 64);
    rv += __shfl_xor(rv, o, 64);
  }
  if (lane == 0) {
    (is_low ? s_l : s_e)[row] = sv;
    (is_low ? r_l : r_e)[row] = rv;
  }
}

// ---------------------------------------------------------------------------
// R22 (resubmit: round 6's bench never acquired a GPU). Latency-bound
// theory (R21 post-mortem: gen time ~45us invariant across 3 schedules,
// all pipes <25% busy -> exposed latency per round).
//  * K-loop: BK=32, 16 rounds, THREE 20,480 B buffers, TWO-round-deep
//    prefetch; counted vmcnt(10/8) -> wait targets loads issued 2 rounds
//    ago (latency fully covered by ~2 rounds of compute).
//  * Triangle grid restored (2*253 = 506 blocks ~ 1.0 generation) with
//    register-adjacent epilogue: pass1 (pairs along j = reg dim) as R21
//    + NEW in-register pass2 (pairs along i = lane dim, off-diag blocks),
//    reusing in-place-transformed de (acce) and raw G (accl). R15-verified
//    orientation conventions (row-side-transformed d for both passes; cLi
//    sign matches R15's verified pass-2 algebra).
//  * LDS swizzle per 64-B row-pair: chunk slot = g ^ (rp&1), parity slot =
//    p ^ ((rp>>1)&1); read-side XOR terms invert it exactly.
// LDS ~66.6 KB -> 2 blocks/CU. MFMA f32_16x16x32_fp8_fp8, operand order
// (col-panel, row-panel): D reg-dim = j, lane&15 = i (R21-verified).
// ---------------------------------------------------------------------------
__global__ __launch_bounds__(256, 2) void fused_sym_kernel(
    const unsigned char* __restrict__ Yq,
    const float* __restrict__ s_l, const float* __restrict__ r_l,
    const float* __restrict__ s_e, const float* __restrict__ r_e,
    float* __restrict__ out) {
  __shared__ __align__(16) long lds_l[7680];   // 3 x 20,480 B staging
  __shared__ __align__(16) float aE[192];      // s_e[i]+2e-6 r_e[i]+epst
  __shared__ __align__(16) float bE[120];      // s_e[j]-2e-6 r_e[j]
  __shared__ __align__(16) float cL[120];      // pass1 j-const
  __shared__ __align__(16) float cLi[192];     // pass2 i-const
  __shared__ float hand[3][112][2];            // de/gl at row 48*w (w=1..3)
  __shared__ float sred[4];

  // decode: blockIdx = 2*tri + half (upper triangle)
  const int half = blockIdx.x & 1;
  int rem = blockIdx.x >> 1, br = 0;
  while (rem >= NT - br) { rem -= NT - br; ++br; }
  const int bc = br + rem;
  const bool diag = (br == bc);
  const bool hasv6 = (half == 0);

  const int tid = threadIdx.x;
  const int lane = tid & 63;
  const int wr = tid >> 6;           // 0..3: rows 48*wr..48*wr+47
  const int quad = lane >> 4, cpos = lane & 15;
  const int r0 = br * TSTRIDE;
  const int cB = bc * TSTRIDE + half * 96;   // block's first global col
  const int tcbase = half * 96;              // block's first tile-local col
  const float epst = (float)DIM * 1e-6f * 1e-6f;

  // ---- prestage epilogue constants ----
  if (tid < 192) {
    const int gi = min(r0 + tid, BROWS - 1);
    const int gi1 = min(r0 + tid + 1, BROWS - 1);
    aE[tid] = s_e[gi] + 2e-6f * r_e[gi] + epst;
    cLi[tid] = (s_l[gi] - s_l[gi1]) + 2e-6f * (r_l[gi] - r_l[gi1]);
  }
  if (tid < 116) {
    const int gj = min(cB + tid, BROWS - 1);
    const int gj1 = min(cB + tid + 1, BROWS - 1);
    bE[tid] = s_e[gj] - 2e-6f * r_e[gj];
    cL[tid] = (s_l[gj] - s_l[gj1]) - 2e-6f * (r_l[gj] - r_l[gj1]);
  }

  // ---- staging map: 1216 slots of 16 B per round, 5/thread (w3: 4) ----
  // segs (slots): A_low [0,384) A_emb [384,768) B_low [768,992) B_emb [992,1216)
  // slot layout per row-pair rp: 4 slots; cc>>1 = parity slot, cc&1 = chunk
  // slot; stored row = 2rp + ((cc>>1)^((rp>>1)&1)), chunk g = (cc&1)^(rp&1).
  int goff[5];
#pragma unroll
  for (int s = 0; s < 5; ++s) {
    const int c = tid + 256 * s;          // 0..1279 (>=1216 unused)
    int seg, base;
    if (c < 384)      { seg = 0; base = 0; }
    else if (c < 768) { seg = 1; base = 384; }
    else if (c < 992) { seg = 2; base = 768; }
    else              { seg = 3; base = 992; }
    const int within = c - base;
    const int rpl = within >> 2, cc = within & 3;
    const int rloc = 2 * rpl + ((cc >> 1) ^ ((rpl >> 1) & 1));
    const int g = (cc & 1) ^ (rpl & 1);
    int rowb;
    if (seg == 0)      rowb = min(r0 + rloc, BROWS - 1) * 512;
    else if (seg == 1) rowb = YEMB_B + min(r0 + rloc, BROWS - 1) * 512;
    else if (seg == 2) rowb = min(cB + rloc, BROWS - 1) * 512;
    else               rowb = YEMB_B + min(cB + rloc, BROWS - 1) * 512;
    goff[s] = rowb + g * 16;
  }

  auto STAGE = [&](int t, int b) {
    const int k0 = t * 32;
#pragma unroll
    for (int s = 0; s < 5; ++s) {
      if (s < 4 || tid < 192)   // w3 skips s=4 (slots >=1216)
        __builtin_amdgcn_global_load_lds(
            (const __attribute__((address_space(1))) void*)(Yq + goff[s] + k0),
            (__attribute__((address_space(3))) void*)(
                ((char*)lds_l) + b * 20480 + (tid + 256 * s) * 16),
            16, 0, 0);
    }
  };

  // ---- frag read offsets (bytes; row-pair stride 64 B, 16 rows = 512 B) ----
  // lane (cpos,quad) reads 8 B at k=8*quad of row (panelrow base + cpos).
  const int RaH = (48 * wr + cpos) >> 1;
  const int offA = RaH * 64 + (((cpos & 1) ^ ((RaH >> 1) & 1)) << 5) +
                   (((quad >> 1) ^ (RaH & 1)) << 4) + (quad & 1) * 8;
  const int RbH = cpos >> 1;
  const int offB = RbH * 64 + (((cpos & 1) ^ ((RbH >> 1) & 1)) << 5) +
                   (((quad >> 1) ^ (RbH & 1)) << 4) + (quad & 1) * 8;
  const int iaL = offA >> 3;               // A_low  (row panel)
  const int iaE = (6144 + offA) >> 3;      // A_emb
  const int ibL = (12288 + offB) >> 3;     // B_low  (col panel)
  const int ibE = (15872 + offB) >> 3;     // B_emb

  f32x4 accl[7][3], acce[7][3];
#pragma unroll
  for (int jb = 0; jb < 7; ++jb)
#pragma unroll
    for (int ib = 0; ib < 3; ++ib) {
      accl[jb][ib] = (f32x4)(0.f);
      acce[jb][ib] = (f32x4)(0.f);
    }

  STAGE(0, 0);   // 2-deep prologue
  STAGE(1, 1);

  int bcur = 0;
  for (int t = 0; t < 16; ++t) {
    if (t < 14) STAGE(t + 2, (t + 2) % 3);
    // counted wait: round-t loads are the oldest; keep t+1 (and t+2) in flight
    if (t < 14) {
      if (wr < 3) asm volatile("s_waitcnt vmcnt(10)" ::: "memory");
      else        asm volatile("s_waitcnt vmcnt(8)" ::: "memory");
    } else if (t == 14) {
      if (wr < 3) asm volatile("s_waitcnt vmcnt(5)" ::: "memory");
      else        asm volatile("s_waitcnt vmcnt(4)" ::: "memory");
    } else {
      asm volatile("s_waitcnt vmcnt(0)" ::: "memory");
    }
    __builtin_amdgcn_s_barrier();
    __builtin_amdgcn_sched_barrier(0);

    const int bo = bcur * 2560;   // buffer offset in longs
    {  // low matrix: p = col-panel (j -> reg dim), q = row-panel (i -> lane)
      long p[7], q[3];
#pragma unroll
      for (int jb = 0; jb < 7; ++jb) p[jb] = lds_l[bo + ibL + jb * 64];
#pragma unroll
      for (int ib = 0; ib < 3; ++ib) q[ib] = lds_l[bo + iaL + ib * 64];
      __builtin_amdgcn_s_setprio(1);
#pragma unroll
      for (int jb = 0; jb < 7; ++jb)
        if (jb < 6 || hasv6)
#pragma unroll
          for (int ib = 0; ib < 3; ++ib)
            accl[jb][ib] = __builtin_amdgcn_mfma_f32_16x16x32_fp8_fp8(
                p[jb], q[ib], accl[jb][ib], 0, 0, 0);
      __builtin_amdgcn_s_setprio(0);
    }
    {  // emb matrix
      long p[7], q[3];
#pragma unroll
      for (int jb = 0; jb < 7; ++jb) p[jb] = lds_l[bo + ibE + jb * 64];
#pragma unroll
      for (int ib = 0; ib < 3; ++ib) q[ib] = lds_l[bo + iaE + ib * 64];
      __builtin_amdgcn_s_setprio(1);
#pragma unroll
      for (int jb = 0; jb < 7; ++jb)
        if (jb < 6 || hasv6)
#pragma unroll
          for (int ib = 0; ib < 3; ++ib)
            acce[jb][ib] = __builtin_amdgcn_mfma_f32_16x16x32_fp8_fp8(
                p[jb], q[ib], acce[jb][ib], 0, 0, 0);
      __builtin_amdgcn_s_setprio(0);
    }
    __builtin_amdgcn_sched_barrier(0);
    __builtin_amdgcn_s_barrier();
    __builtin_amdgcn_sched_barrier(0);
    bcur = (bcur == 2) ? 0 : bcur + 1;
  }

  // ---- transform acce in place -> de (row-side d); accl stays raw G ----
#pragma unroll
  for (int ib = 0; ib < 3; ++ib) {
    const float ai = aE[48 * wr + 16 * ib + cpos];
#pragma unroll
    for (int jb = 0; jb < 7; ++jb) {
      const float4 be4 = ((const float4*)bE)[4 * jb + quad];
#pragma unroll
      for (int r = 0; r < 4; ++r)
        acce[jb][ib][r] = sqrtf(fmaxf(ai + be4[r] - 2.f * acce[jb][ib][r], 0.f));
    }
  }

  // ---- publish wave-boundary row (i = 48*wr, ib=0) for wave wr-1 ----
  if (wr >= 1 && cpos == 0) {
#pragma unroll
    for (int jb = 0; jb < 7; ++jb)
#pragma unroll
      for (int r = 0; r < 4; ++r) {
        hand[wr - 1][16 * jb + 4 * quad + r][0] = acce[jb][0][r];
        hand[wr - 1][16 * jb + 4 * quad + r][1] = accl[jb][0][r];
      }
  }
  __syncthreads();

  float sum = 0.f;

  // ---- pass 1: pairs along j (reg dim) ----
#pragma unroll
  for (int ib = 0; ib < 3; ++ib) {
    const int irow = 48 * wr + 16 * ib + cpos;
    const int gi = r0 + irow;
    const bool rowok = (irow <= TSTRIDE - 1) && (gi <= BROWS - 2);
#pragma unroll
    for (int jb = 0; jb < 6; ++jb) {
      const float deq = __shfl(acce[jb][ib][0], (lane + 16) & 63, 64);
      const float glq = __shfl(accl[jb][ib][0], (lane + 16) & 63, 64);
      const float dec = __shfl(acce[jb + 1][ib][0], lane & 15, 64);
      const float glc = __shfl(accl[jb + 1][ib][0], lane & 15, 64);
      const float de2r3 = (quad < 3) ? deq : dec;
      const float gl2r3 = (quad < 3) ? glq : glc;
      const float4 cl4 = ((const float4*)cL)[4 * jb + quad];
#pragma unroll
      for (int r = 0; r < 4; ++r) {
        const float de1 = acce[jb][ib][r], g1 = accl[jb][ib][r];
        const float de2 = (r < 3) ? acce[jb][ib][r + 1] : de2r3;
        const float g2 = (r < 3) ? accl[jb][ib][r + 1] : gl2r3;
        const float x = de2 - de1;
        const float Dl = cl4[r] - 2.f * (g1 - g2);
        const float term = fabsf(x) + (Dl > 0.f ? x : (Dl < 0.f ? -x : 0.f));
        const int c1 = 16 * jb + 4 * quad + r;
        if (rowok && tcbase + c1 <= TSTRIDE - 1 && cB + c1 <= BROWS - 3)
          sum += term;
      }
    }
  }

  // ---- pass 2: pairs along i (lane dim), off-diag blocks only ----
  if (!diag) {
    const int hw = (wr < 3) ? wr : 2;   // hand row (wr==3 terms filtered)
#pragma unroll
    for (int ib = 0; ib < 3; ++ib) {
      const int irow = 48 * wr + 16 * ib + cpos;
      const int gi = r0 + irow;
      const bool bok = (irow <= TSTRIDE - 1) && (gi <= BROWS - 3);
      const float cli = cLi[irow];
#pragma unroll
      for (int jb = 0; jb < 6; ++jb) {
#pragma unroll
        for (int r = 0; r < 4; ++r) {
          const float de1 = acce[jb][ib][r], g1 = accl[jb][ib][r];
          const int srcn = (lane & 48) | ((cpos + 1) & 15);
          float de2 = __shfl(de1, srcn, 64);
          float g2 = __shfl(g1, srcn, 64);
          if (ib < 2) {
            const float dei = __shfl(acce[jb][ib + 1][r], lane & 48, 64);
            const float gli = __shfl(accl[jb][ib + 1][r], lane & 48, 64);
            if (cpos == 15) { de2 = dei; g2 = gli; }
          } else {
            const int a = 16 * jb + 4 * quad + r;
            if (cpos == 15) { de2 = hand[hw][a][0]; g2 = hand[hw][a][1]; }
          }
          const float x = de2 - de1;
          const float Dl = cli - 2.f * (g1 - g2);
          const float term = fabsf(x) + (Dl > 0.f ? x : (Dl < 0.f ? -x : 0.f));
          const int a = 16 * jb + 4 * quad + r;
          if (bok && tcbase + a <= TSTRIDE - 1 && cB + a <= BROWS - 2)
            sum += term;
        }
      }
    }
  }

  // ---- reduce + atomic ----
#pragma unroll
  for (int o = 32; o; o >>= 1) sum += __shfl_down(sum, o, 64);
  if (lane == 0) sred[wr] = sum;
  __syncthreads();
  if (tid == 0) {
    const float scale = 1.0f / ((float)(BROWS - 1) * (float)(BROWS - 2));
    float t = 0.f;
#pragma unroll
    for (int w = 0; w < 4; ++w) t += sred[w];
    atomicAdd(out, t * scale);
  }
}

// ===========================================================================
extern "C" void kernel_launch(void* const* d_in, const int* in_sizes, int n_in,
                              void* d_out, int out_size, void* d_ws,
                              size_t ws_size, hipStream_t stream) {
  const float* low = (const float*)d_in[0];
  const float* emb = (const float*)d_in[1];
  float* out = (float*)d_out;

  // ws: Yq (2*4096*512 fp8 = 4 MB) then s_l, r_l, s_e, r_e (4096 f32 each)
  unsigned char* Yq = (unsigned char*)d_ws;
  float* s_l = (float*)(Yq + 2 * (size_t)BROWS * DIM);
  float* r_l = s_l + BROWS;
  float* s_e = r_l + BROWS;
  float* r_e = s_e + BROWS;

  prep4_kernel<<<2 * BROWS / 4, 256, 0, stream>>>(low, emb, Yq, s_l, r_l, s_e, r_e, out);
  fused_sym_kernel<<<NT * (NT + 1), 256, 0, stream>>>(Yq, s_l, r_l, s_e, r_e, out);
}

// Round 11
// 108.877 us; speedup vs baseline: 1.2704x; 1.2704x over previous
//
#include <hip/hip_runtime.h>
#include <hip/hip_bf16.h>
#include <hip/hip_fp8.h>
#include <math.h>

#define BROWS 4096
#define DIM   512
#define YEMB_B 2097152   // 4096*512 bytes, offset of emb rows in Yq (fp8)
#define TSTRIDE 191      // tile stride (tiles are 192 wide, overlap by 1)
#define NT 22            // tiles per dim; triangle blocks = 22*23/2 = 253

typedef float f32x4 __attribute__((ext_vector_type(4)));

// ---------------------------------------------------------------------------
// prep4: wave-per-row, no barriers. 8192 rows (low then emb), 4 rows/block.
// L2-normalize -> fp8 e4m3 row in Yq; s=sum(y^2), r=sum(y) from f32 y.
// (verified R12-R18: absmax 0.0)
// ---------------------------------------------------------------------------
__global__ __launch_bounds__(256) void prep4_kernel(
    const float* __restrict__ low, const float* __restrict__ emb,
    unsigned char* __restrict__ Yq,
    float* __restrict__ s_l, float* __restrict__ r_l,
    float* __restrict__ s_e, float* __restrict__ r_e,
    float* __restrict__ out) {
  const int tid = threadIdx.x;
  const int lane = tid & 63, wid = tid >> 6;
  const int rid = blockIdx.x * 4 + wid;          // 0..8191
  if (blockIdx.x == 0 && tid == 0) out[0] = 0.f;

  const bool is_low = (rid < BROWS);
  const int row = is_low ? rid : rid - BROWS;
  const float* x = (is_low ? low : emb) + (size_t)row * DIM;

  const float4 v0 = ((const float4*)x)[lane * 2];
  const float4 v1 = ((const float4*)x)[lane * 2 + 1];

  float ss = v0.x * v0.x + v0.y * v0.y + v0.z * v0.z + v0.w * v0.w +
             v1.x * v1.x + v1.y * v1.y + v1.z * v1.z + v1.w * v1.w;
#pragma unroll
  for (int o = 1; o < 64; o <<= 1) ss += __shfl_xor(ss, o, 64);
  const float inv = 1.0f / fmaxf(sqrtf(ss), 1e-12f);

  float y[8] = {v0.x * inv, v0.y * inv, v0.z * inv, v0.w * inv,
                v1.x * inv, v1.y * inv, v1.z * inv, v1.w * inv};

  union { unsigned char b[8]; unsigned long long u; } pk;
  float sv = 0.f, rv = 0.f;
#pragma unroll
  for (int i = 0; i < 8; ++i) {
    pk.b[i] = __hip_fp8_e4m3(y[i]).__x;   // OCP e4m3fn, HW RNE
    sv += y[i] * y[i];
    rv += y[i];
  }
  ((unsigned long long*)(Yq + (size_t)rid * 512))[lane] = pk.u;

#pragma unroll
  for (int o = 1; o < 64; o <<= 1) {
    sv += __shfl_xor(sv, o, 64);
    rv += __shfl_xor(rv, o, 64);
  }
  if (lane == 0) {
    (is_low ? s_l : s_e)[row] = sv;
    (is_low ? r_l : r_e)[row] = rv;
  }
}

// ---------------------------------------------------------------------------
// R26 = exact resubmit of R18 (best measured this session: 108.46 us total,
// fused 44.84 us, absmax 0.0, no spill). Rounds 7-10: four consecutive GPU
// acquisition timeouts; banking the verified best.
// Geometry: 192x192 tiles (stride 191), NT=22 -> 253 blocks, 512 thr,
// 8 waves 4x2, wave tile 48x96 per matrix, acc 144 regs under (512,2) cap.
// K-loop: BK=64, 8 rounds, double-buffered 2x48 KB, counted vmcnt(6/3),
// never 0 until last round. LDS ~104 KB -> 1 block/CU, zero tail.
// MFMA f32_16x16x32_fp8_fp8; C/D: col=lane&15, row=(lane>>4)*4+reg.
// Epilogue: direct + transposed (symmetry) pair terms, shfl + LDS hands.
// ---------------------------------------------------------------------------
__global__ __launch_bounds__(512, 2) void fused_sym_kernel(
    const unsigned char* __restrict__ Yq,
    const float* __restrict__ s_l, const float* __restrict__ r_l,
    const float* __restrict__ s_e, const float* __restrict__ r_e,
    float* __restrict__ out) {
  __shared__ __align__(16) unsigned char lds8[98304];  // 2 x 48 KB buffers
  __shared__ float hand_d[4][48][2];    // dl/de at tile col 96, per wr
  __shared__ float hand_t[4][192][2];   // dl/de at tile row 48*wr ([wr-1])
  __shared__ float sred[8];

  // decode upper-triangle block id
  int rem = blockIdx.x, br = 0;
  while (rem >= NT - br) { rem -= NT - br; ++br; }
  const int bc = br + rem;
  const bool diag = (br == bc);

  const int tid = threadIdx.x;
  const int lane = tid & 63;
  const int wid = tid >> 6;          // 0..7
  const int wr = wid >> 1;           // 0..3: rows 48*wr..48*wr+47
  const int wc = wid & 1;            // 0..1: cols 96*wc..96*wc+95
  const int quad = lane >> 4, cpos = lane & 15;
  const int r0 = br * TSTRIDE, c0 = bc * TSTRIDE;

  // staging: 3072 slots of 16B per round (4 segs x 96 rp x 8 chunks);
  // thread owns slot c = tid + 512*s, s=0..5.  A segs = s<3, B segs = s>=3.
  int goff[6];   // BYTE offsets into Yq (add k0 = t*64 per round)
#pragma unroll
  for (int s = 0; s < 6; ++s) {
    const int c = tid + 512 * s;          // 0..3071
    const int seg = c / 768;
    const int within = c - seg * 768;
    const int rp = within >> 3;           // 0..95
    const int cc = within & 7;
    const int rloc = 2 * rp + (cc >> 2);
    const int gch = (cc & 3) ^ (rp & 3);  // swizzle
    int base;
    if (seg == 0)      base = min(r0 + rloc, BROWS - 1) * 512;
    else if (seg == 1) base = YEMB_B + min(r0 + rloc, BROWS - 1) * 512;
    else if (seg == 2) base = min(c0 + rloc, BROWS - 1) * 512;
    else               base = YEMB_B + min(c0 + rloc, BROWS - 1) * 512;
    goff[s] = base + (gch << 4);
  }

  auto STAGE = [&](int t, int b) {
    const int k0 = t * 64;
#pragma unroll
    for (int s = 0; s < 6; ++s) {
      if (s < 3 || !diag)   // s>=3 are B segments; skip when diag
        __builtin_amdgcn_global_load_lds(
            (const __attribute__((address_space(1))) void*)(Yq + goff[s] + k0),
            (__attribute__((address_space(3))) void*)(lds8 + b * 49152 +
                                                      (tid + 512 * s) * 16),
            16, 0, 0);
    }
  };

  // frag addressing (per 48 KB buffer): seg bytes Alow 0, Aemb 12288,
  // Blow 24576 (0 if diag), Bemb 36864 (12288 if diag); row-pair stride
  // 128 B; u/v stride 16 rows = 8 rp = 1024 B.
  const int RaH = (48 * wr + cpos) >> 1;     // row-pair idx (48wr even)
  const int s3a = RaH & 3;
  const int aoff = RaH * 128 + (cpos & 1) * 64 + (quad & 1) * 8;
  const int RbH = (96 * wc + cpos) >> 1;
  const int s3b = RbH & 3;
  const int boff = RbH * 128 + (cpos & 1) * 64 + (quad & 1) * 8;
  const int segAL = 0, segAE = 12288;
  const int segBL = diag ? 0 : 24576;
  const int segBE = diag ? 12288 : 36864;

  f32x4 accl[3][6], acce[3][6];
#pragma unroll
  for (int u = 0; u < 3; ++u)
#pragma unroll
    for (int v = 0; v < 6; ++v) {
      accl[u][v] = (f32x4)(0.f);
      acce[u][v] = (f32x4)(0.f);
    }

  STAGE(0, 0);   // prologue prefetch

  for (int t = 0; t < 8; ++t) {
    if (t < 7) STAGE(t + 1, (t + 1) & 1);   // buf free since barrier2 of t-1
    // counted wait: oldest 6 (3 diag) loads = round t's; keep t+1's in flight
    if (t == 7)      asm volatile("s_waitcnt vmcnt(0)" ::: "memory");
    else if (diag)   asm volatile("s_waitcnt vmcnt(3)" ::: "memory");
    else             asm volatile("s_waitcnt vmcnt(6)" ::: "memory");
    __builtin_amdgcn_s_barrier();
    __builtin_amdgcn_sched_barrier(0);

    const unsigned char* Lb = lds8 + (t & 1) * 49152;
#pragma unroll
    for (int kk = 0; kk < 2; ++kk) {
      const int q = 2 * kk + (quad >> 1);          // 16B chunk 0..3
      const int cha = aoff + ((q ^ s3a) << 4);
      const int chb = boff + ((q ^ s3b) << 4);
      {  // low matrix
        long a[3], b[6];
#pragma unroll
        for (int u = 0; u < 3; ++u) a[u] = *(const long*)(Lb + segAL + cha + u * 1024);
#pragma unroll
        for (int v = 0; v < 6; ++v) b[v] = *(const long*)(Lb + segBL + chb + v * 1024);
        __builtin_amdgcn_s_setprio(1);
#pragma unroll
        for (int u = 0; u < 3; ++u)
#pragma unroll
          for (int v = 0; v < 6; ++v)
            accl[u][v] = __builtin_amdgcn_mfma_f32_16x16x32_fp8_fp8(
                a[u], b[v], accl[u][v], 0, 0, 0);
        __builtin_amdgcn_s_setprio(0);
      }
      {  // emb matrix
        long a[3], b[6];
#pragma unroll
        for (int u = 0; u < 3; ++u) a[u] = *(const long*)(Lb + segAE + cha + u * 1024);
#pragma unroll
        for (int v = 0; v < 6; ++v) b[v] = *(const long*)(Lb + segBE + chb + v * 1024);
        __builtin_amdgcn_s_setprio(1);
#pragma unroll
        for (int u = 0; u < 3; ++u)
#pragma unroll
          for (int v = 0; v < 6; ++v)
            acce[u][v] = __builtin_amdgcn_mfma_f32_16x16x32_fp8_fp8(
                a[u], b[v], acce[u][v], 0, 0, 0);
        __builtin_amdgcn_s_setprio(0);
      }
    }
    __builtin_amdgcn_sched_barrier(0);
    __builtin_amdgcn_s_barrier();
    __builtin_amdgcn_sched_barrier(0);
  }

  // ---- transform both accs -> distances in place ----
  const float epst = (float)DIM * 1e-6f * 1e-6f;
#pragma unroll
  for (int v = 0; v < 6; ++v) {
    const int j = min(c0 + 96 * wc + 16 * v + cpos, BROWS - 1);
    const float sjl = s_l[j], rjl = r_l[j];
    const float sje = s_e[j], rje = r_e[j];
#pragma unroll
    for (int u = 0; u < 3; ++u)
#pragma unroll
      for (int r = 0; r < 4; ++r) {
        const int i = min(r0 + 48 * wr + 16 * u + 4 * quad + r, BROWS - 1);
        const float sql = s_l[i] + sjl - 2.f * accl[u][v][r] +
                          2e-6f * (r_l[i] - rjl) + epst;
        accl[u][v][r] = sqrtf(fmaxf(sql, 0.f));
        const float sqe = s_e[i] + sje - 2.f * acce[u][v][r] +
                          2e-6f * (r_e[i] - rje) + epst;
        acce[u][v][r] = sqrtf(fmaxf(sqe, 0.f));
      }
  }
  // now: dl in accl, de in acce

  // ---- publish cross-wave boundary values (dl and de) ----
  if (wc == 1 && cpos == 0) {   // tile col 96 for this wr's 48 rows
#pragma unroll
    for (int u = 0; u < 3; ++u)
#pragma unroll
      for (int r = 0; r < 4; ++r) {
        hand_d[wr][16 * u + 4 * quad + r][0] = accl[u][0][r];
        hand_d[wr][16 * u + 4 * quad + r][1] = acce[u][0][r];
      }
  }
  if (quad == 0 && wr >= 1) {   // tile row 48*wr (u=0,r=0) for 96 cols
#pragma unroll
    for (int v = 0; v < 6; ++v) {
      hand_t[wr - 1][96 * wc + 16 * v + cpos][0] = accl[0][v][0];
      hand_t[wr - 1][96 * wc + 16 * v + cpos][1] = acce[0][v][0];
    }
  }
  __syncthreads();

  float sum = 0.f;

  // ---- pass 1: direct terms (i in rows, pair cols j,j+1) ----
  const int srcin = (lane & 48) | ((cpos + 1) & 15);
#pragma unroll
  for (int u = 0; u < 3; ++u)
#pragma unroll
    for (int r = 0; r < 4; ++r) {
      const int trow = 48 * wr + 16 * u + 4 * quad + r;
      const int i = r0 + trow;
      const bool rowok = (trow <= TSTRIDE - 1) && (i <= BROWS - 2);
#pragma unroll
      for (int v = 0; v < 6; ++v) {
        const float dl1 = accl[u][v][r], de1 = acce[u][v][r];
        float dl2 = __shfl(dl1, srcin, 64);
        float de2 = __shfl(de1, srcin, 64);
        if (v < 5) {
          const float dlb = __shfl(accl[u][v + 1][r], lane & 48, 64);
          const float deb = __shfl(acce[u][v + 1][r], lane & 48, 64);
          if (cpos == 15) { dl2 = dlb; de2 = deb; }
        } else if (cpos == 15 && wc == 0) {
          dl2 = hand_d[wr][16 * u + 4 * quad + r][0];
          de2 = hand_d[wr][16 * u + 4 * quad + r][1];
        }
        const int tcol = 96 * wc + 16 * v + cpos;
        const int j = c0 + tcol;
        if (rowok && tcol <= TSTRIDE - 1 && j <= BROWS - 3) {
          const float aa = dl1 - dl2, bb = de1 - de2;
          const float coeff = (float)((aa > 0.f) - (aa < 0.f)) -
                              (float)((bb > 0.f) - (bb < 0.f));
          sum += coeff * (de2 - de1);
        }
      }
    }

  // ---- pass 2: transposed terms (i in cols, pair rows j,j+1), off-diag only ----
  if (!diag) {
#pragma unroll
    for (int u = 0; u < 3; ++u)
#pragma unroll
      for (int v = 0; v < 6; ++v) {
        const int tcol = 96 * wc + 16 * v + cpos;
        const int ii = c0 + tcol;
        const bool colok = (tcol <= TSTRIDE - 1) && (ii <= BROWS - 2);
#pragma unroll
        for (int r = 0; r < 4; ++r) {
          const int trow = 48 * wr + 16 * u + 4 * quad + r;
          const int jj = r0 + trow;
          float dl2, de2;
          if (r < 3) {
            dl2 = accl[u][v][r + 1];
            de2 = acce[u][v][r + 1];
          } else {
            const float dlq = __shfl(accl[u][v][0], (lane + 16) & 63, 64);
            const float deq = __shfl(acce[u][v][0], (lane + 16) & 63, 64);
            const int un = (u < 2) ? u + 1 : u;
            const float dlu = __shfl(accl[un][v][0], cpos, 64);
            const float deu = __shfl(acce[un][v][0], cpos, 64);
            if (quad < 3)    { dl2 = dlq; de2 = deq; }
            else if (u < 2)  { dl2 = dlu; de2 = deu; }
            else             { dl2 = hand_t[wr][tcol][0];   // wr==3 filtered
                               de2 = hand_t[wr][tcol][1]; }
          }
          if (colok && trow <= TSTRIDE - 1 && jj <= BROWS - 3) {
            const float dl1 = accl[u][v][r], de1 = acce[u][v][r];
            const float aa = dl1 - dl2, bb = de1 - de2;
            const float coeff = (float)((aa > 0.f) - (aa < 0.f)) -
                                (float)((bb > 0.f) - (bb < 0.f));
            sum += coeff * (de2 - de1);
          }
        }
      }
  }

  // ---- reduce + atomic ----
#pragma unroll
  for (int o = 32; o; o >>= 1) sum += __shfl_down(sum, o, 64);
  if (lane == 0) sred[wid] = sum;
  __syncthreads();
  if (tid == 0) {
    const float scale = 1.0f / ((float)(BROWS - 1) * (float)(BROWS - 2));
    float t = 0.f;
#pragma unroll
    for (int w = 0; w < 8; ++w) t += sred[w];
    atomicAdd(out, t * scale);
  }
}

// ===========================================================================
extern "C" void kernel_launch(void* const* d_in, const int* in_sizes, int n_in,
                              void* d_out, int out_size, void* d_ws,
                              size_t ws_size, hipStream_t stream) {
  const float* low = (const float*)d_in[0];
  const float* emb = (const float*)d_in[1];
  float* out = (float*)d_out;

  // ws: Yq (2*4096*512 fp8 = 4 MB) then s_l, r_l, s_e, r_e (4096 f32 each)
  unsigned char* Yq = (unsigned char*)d_ws;
  float* s_l = (float*)(Yq + 2 * (size_t)BROWS * DIM);
  float* r_l = s_l + BROWS;
  float* s_e = r_l + BROWS;
  float* r_e = s_e + BROWS;

  prep4_kernel<<<2 * BROWS / 4, 256, 0, stream>>>(low, emb, Yq, s_l, r_l, s_e, r_e, out);
  fused_sym_kernel<<<NT * (NT + 1) / 2, 512, 0, stream>>>(Yq, s_l, r_l, s_e, r_e, out);
}

// Round 12
// 108.854 us; speedup vs baseline: 1.2707x; 1.0002x over previous
//
#include <hip/hip_runtime.h>
#include <hip/hip_bf16.h>
#include <hip/hip_fp8.h>
#include <math.h>

#define BROWS 4096
#define DIM   512
#define YEMB_B 2097152   // 4096*512 bytes, offset of emb rows in Yq (fp8)
#define TSTRIDE 191      // tile stride (tiles are 192 wide, overlap by 1)
#define NT 22            // tiles per dim; triangle blocks = 22*23/2 = 253

typedef float f32x4 __attribute__((ext_vector_type(4)));

// ---------------------------------------------------------------------------
// prep4: wave-per-row, no barriers. 8192 rows (low then emb), 4 rows/block.
// L2-normalize -> fp8 e4m3 row in Yq; s=sum(y^2), r=sum(y) from f32 y.
// (verified R12-R26: absmax 0.0)
// ---------------------------------------------------------------------------
__global__ __launch_bounds__(256) void prep4_kernel(
    const float* __restrict__ low, const float* __restrict__ emb,
    unsigned char* __restrict__ Yq,
    float* __restrict__ s_l, float* __restrict__ r_l,
    float* __restrict__ s_e, float* __restrict__ r_e,
    float* __restrict__ out) {
  const int tid = threadIdx.x;
  const int lane = tid & 63, wid = tid >> 6;
  const int rid = blockIdx.x * 4 + wid;          // 0..8191
  if (blockIdx.x == 0 && tid == 0) out[0] = 0.f;

  const bool is_low = (rid < BROWS);
  const int row = is_low ? rid : rid - BROWS;
  const float* x = (is_low ? low : emb) + (size_t)row * DIM;

  const float4 v0 = ((const float4*)x)[lane * 2];
  const float4 v1 = ((const float4*)x)[lane * 2 + 1];

  float ss = v0.x * v0.x + v0.y * v0.y + v0.z * v0.z + v0.w * v0.w +
             v1.x * v1.x + v1.y * v1.y + v1.z * v1.z + v1.w * v1.w;
#pragma unroll
  for (int o = 1; o < 64; o <<= 1) ss += __shfl_xor(ss, o, 64);
  const float inv = 1.0f / fmaxf(sqrtf(ss), 1e-12f);

  float y[8] = {v0.x * inv, v0.y * inv, v0.z * inv, v0.w * inv,
                v1.x * inv, v1.y * inv, v1.z * inv, v1.w * inv};

  union { unsigned char b[8]; unsigned long long u; } pk;
  float sv = 0.f, rv = 0.f;
#pragma unroll
  for (int i = 0; i < 8; ++i) {
    pk.b[i] = __hip_fp8_e4m3(y[i]).__x;   // OCP e4m3fn, HW RNE
    sv += y[i] * y[i];
    rv += y[i];
  }
  ((unsigned long long*)(Yq + (size_t)rid * 512))[lane] = pk.u;

#pragma unroll
  for (int o = 1; o < 64; o <<= 1) {
    sv += __shfl_xor(sv, o, 64);
    rv += __shfl_xor(rv, o, 64);
  }
  if (lane == 0) {
    (is_low ? s_l : s_e)[row] = sv;
    (is_low ? r_l : r_e)[row] = rv;
  }
}

// ---------------------------------------------------------------------------
// R27 = R18 (twice-verified: 108.46/108.88 us total, fused 44.84, absmax 0.0)
// + ONE change: bijective XCD-aware blockIdx swizzle (T1, m204 formula).
// Theory: staged-bytes-vs-time fit across R19/R21 is exactly proportional
// (615KB/CU->47.4us, 1176KB/CU->90us; ratio 1.91=1.91) at ~3.3-4.3 TB/s
// aggregate -> staging is cross-XCD L3/fabric-bandwidth-bound (Yq written
// scattered by prep4; default round-robin dispatch gives readers ~7/8
// cross-XCD panels). Swizzle gives each XCD ~32 CONTIGUOUS tri blocks ->
// shared br => A panels (192 KB << 4 MiB L2/XCD) become XCD-local with
// 16-32x reuse, halving L3 read traffic. All else byte-identical to R18.
// Geometry: 192x192 tiles (stride 191), 253 blocks, 512 thr, 8 waves 4x2,
// BK=64 x 8 rounds, dbuf 2x48KB, counted vmcnt(6/3), LDS ~104KB, 1 blk/CU.
// MFMA f32_16x16x32_fp8_fp8; C/D: col=lane&15, row=(lane>>4)*4+reg.
// ---------------------------------------------------------------------------
__global__ __launch_bounds__(512, 2) void fused_sym_kernel(
    const unsigned char* __restrict__ Yq,
    const float* __restrict__ s_l, const float* __restrict__ r_l,
    const float* __restrict__ s_e, const float* __restrict__ r_e,
    float* __restrict__ out) {
  __shared__ __align__(16) unsigned char lds8[98304];  // 2 x 48 KB buffers
  __shared__ float hand_d[4][48][2];    // dl/de at tile col 96, per wr
  __shared__ float hand_t[4][192][2];   // dl/de at tile row 48*wr ([wr-1])
  __shared__ float sred[8];

  // ---- XCD-aware bijective swizzle (nwg=253, 8 XCDs: q=31, r=5) ----
  // xcd<5 own 32 consecutive tri ids, xcd>=5 own 31. Assumes round-robin
  // bid->XCD dispatch; if mapping differs this only affects locality.
  const int xcd = blockIdx.x & 7;
  const int ii_ = blockIdx.x >> 3;
  const int tri = (xcd < 5 ? xcd * 32 : 160 + (xcd - 5) * 31) + ii_;

  // decode upper-triangle block id
  int rem = tri, br = 0;
  while (rem >= NT - br) { rem -= NT - br; ++br; }
  const int bc = br + rem;
  const bool diag = (br == bc);

  const int tid = threadIdx.x;
  const int lane = tid & 63;
  const int wid = tid >> 6;          // 0..7
  const int wr = wid >> 1;           // 0..3: rows 48*wr..48*wr+47
  const int wc = wid & 1;            // 0..1: cols 96*wc..96*wc+95
  const int quad = lane >> 4, cpos = lane & 15;
  const int r0 = br * TSTRIDE, c0 = bc * TSTRIDE;

  // staging: 3072 slots of 16B per round (4 segs x 96 rp x 8 chunks);
  // thread owns slot c = tid + 512*s, s=0..5.  A segs = s<3, B segs = s>=3.
  int goff[6];   // BYTE offsets into Yq (add k0 = t*64 per round)
#pragma unroll
  for (int s = 0; s < 6; ++s) {
    const int c = tid + 512 * s;          // 0..3071
    const int seg = c / 768;
    const int within = c - seg * 768;
    const int rp = within >> 3;           // 0..95
    const int cc = within & 7;
    const int rloc = 2 * rp + (cc >> 2);
    const int gch = (cc & 3) ^ (rp & 3);  // swizzle
    int base;
    if (seg == 0)      base = min(r0 + rloc, BROWS - 1) * 512;
    else if (seg == 1) base = YEMB_B + min(r0 + rloc, BROWS - 1) * 512;
    else if (seg == 2) base = min(c0 + rloc, BROWS - 1) * 512;
    else               base = YEMB_B + min(c0 + rloc, BROWS - 1) * 512;
    goff[s] = base + (gch << 4);
  }

  auto STAGE = [&](int t, int b) {
    const int k0 = t * 64;
#pragma unroll
    for (int s = 0; s < 6; ++s) {
      if (s < 3 || !diag)   // s>=3 are B segments; skip when diag
        __builtin_amdgcn_global_load_lds(
            (const __attribute__((address_space(1))) void*)(Yq + goff[s] + k0),
            (__attribute__((address_space(3))) void*)(lds8 + b * 49152 +
                                                      (tid + 512 * s) * 16),
            16, 0, 0);
    }
  };

  // frag addressing (per 48 KB buffer): seg bytes Alow 0, Aemb 12288,
  // Blow 24576 (0 if diag), Bemb 36864 (12288 if diag); row-pair stride
  // 128 B; u/v stride 16 rows = 8 rp = 1024 B.
  const int RaH = (48 * wr + cpos) >> 1;     // row-pair idx (48wr even)
  const int s3a = RaH & 3;
  const int aoff = RaH * 128 + (cpos & 1) * 64 + (quad & 1) * 8;
  const int RbH = (96 * wc + cpos) >> 1;
  const int s3b = RbH & 3;
  const int boff = RbH * 128 + (cpos & 1) * 64 + (quad & 1) * 8;
  const int segAL = 0, segAE = 12288;
  const int segBL = diag ? 0 : 24576;
  const int segBE = diag ? 12288 : 36864;

  f32x4 accl[3][6], acce[3][6];
#pragma unroll
  for (int u = 0; u < 3; ++u)
#pragma unroll
    for (int v = 0; v < 6; ++v) {
      accl[u][v] = (f32x4)(0.f);
      acce[u][v] = (f32x4)(0.f);
    }

  STAGE(0, 0);   // prologue prefetch

  for (int t = 0; t < 8; ++t) {
    if (t < 7) STAGE(t + 1, (t + 1) & 1);   // buf free since barrier2 of t-1
    // counted wait: oldest 6 (3 diag) loads = round t's; keep t+1's in flight
    if (t == 7)      asm volatile("s_waitcnt vmcnt(0)" ::: "memory");
    else if (diag)   asm volatile("s_waitcnt vmcnt(3)" ::: "memory");
    else             asm volatile("s_waitcnt vmcnt(6)" ::: "memory");
    __builtin_amdgcn_s_barrier();
    __builtin_amdgcn_sched_barrier(0);

    const unsigned char* Lb = lds8 + (t & 1) * 49152;
#pragma unroll
    for (int kk = 0; kk < 2; ++kk) {
      const int q = 2 * kk + (quad >> 1);          // 16B chunk 0..3
      const int cha = aoff + ((q ^ s3a) << 4);
      const int chb = boff + ((q ^ s3b) << 4);
      {  // low matrix
        long a[3], b[6];
#pragma unroll
        for (int u = 0; u < 3; ++u) a[u] = *(const long*)(Lb + segAL + cha + u * 1024);
#pragma unroll
        for (int v = 0; v < 6; ++v) b[v] = *(const long*)(Lb + segBL + chb + v * 1024);
        __builtin_amdgcn_s_setprio(1);
#pragma unroll
        for (int u = 0; u < 3; ++u)
#pragma unroll
          for (int v = 0; v < 6; ++v)
            accl[u][v] = __builtin_amdgcn_mfma_f32_16x16x32_fp8_fp8(
                a[u], b[v], accl[u][v], 0, 0, 0);
        __builtin_amdgcn_s_setprio(0);
      }
      {  // emb matrix
        long a[3], b[6];
#pragma unroll
        for (int u = 0; u < 3; ++u) a[u] = *(const long*)(Lb + segAE + cha + u * 1024);
#pragma unroll
        for (int v = 0; v < 6; ++v) b[v] = *(const long*)(Lb + segBE + chb + v * 1024);
        __builtin_amdgcn_s_setprio(1);
#pragma unroll
        for (int u = 0; u < 3; ++u)
#pragma unroll
          for (int v = 0; v < 6; ++v)
            acce[u][v] = __builtin_amdgcn_mfma_f32_16x16x32_fp8_fp8(
                a[u], b[v], acce[u][v], 0, 0, 0);
        __builtin_amdgcn_s_setprio(0);
      }
    }
    __builtin_amdgcn_sched_barrier(0);
    __builtin_amdgcn_s_barrier();
    __builtin_amdgcn_sched_barrier(0);
  }

  // ---- transform both accs -> distances in place ----
  const float epst = (float)DIM * 1e-6f * 1e-6f;
#pragma unroll
  for (int v = 0; v < 6; ++v) {
    const int j = min(c0 + 96 * wc + 16 * v + cpos, BROWS - 1);
    const float sjl = s_l[j], rjl = r_l[j];
    const float sje = s_e[j], rje = r_e[j];
#pragma unroll
    for (int u = 0; u < 3; ++u)
#pragma unroll
      for (int r = 0; r < 4; ++r) {
        const int i = min(r0 + 48 * wr + 16 * u + 4 * quad + r, BROWS - 1);
        const float sql = s_l[i] + sjl - 2.f * accl[u][v][r] +
                          2e-6f * (r_l[i] - rjl) + epst;
        accl[u][v][r] = sqrtf(fmaxf(sql, 0.f));
        const float sqe = s_e[i] + sje - 2.f * acce[u][v][r] +
                          2e-6f * (r_e[i] - rje) + epst;
        acce[u][v][r] = sqrtf(fmaxf(sqe, 0.f));
      }
  }
  // now: dl in accl, de in acce

  // ---- publish cross-wave boundary values (dl and de) ----
  if (wc == 1 && cpos == 0) {   // tile col 96 for this wr's 48 rows
#pragma unroll
    for (int u = 0; u < 3; ++u)
#pragma unroll
      for (int r = 0; r < 4; ++r) {
        hand_d[wr][16 * u + 4 * quad + r][0] = accl[u][0][r];
        hand_d[wr][16 * u + 4 * quad + r][1] = acce[u][0][r];
      }
  }
  if (quad == 0 && wr >= 1) {   // tile row 48*wr (u=0,r=0) for 96 cols
#pragma unroll
    for (int v = 0; v < 6; ++v) {
      hand_t[wr - 1][96 * wc + 16 * v + cpos][0] = accl[0][v][0];
      hand_t[wr - 1][96 * wc + 16 * v + cpos][1] = acce[0][v][0];
    }
  }
  __syncthreads();

  float sum = 0.f;

  // ---- pass 1: direct terms (i in rows, pair cols j,j+1) ----
  const int srcin = (lane & 48) | ((cpos + 1) & 15);
#pragma unroll
  for (int u = 0; u < 3; ++u)
#pragma unroll
    for (int r = 0; r < 4; ++r) {
      const int trow = 48 * wr + 16 * u + 4 * quad + r;
      const int i = r0 + trow;
      const bool rowok = (trow <= TSTRIDE - 1) && (i <= BROWS - 2);
#pragma unroll
      for (int v = 0; v < 6; ++v) {
        const float dl1 = accl[u][v][r], de1 = acce[u][v][r];
        float dl2 = __shfl(dl1, srcin, 64);
        float de2 = __shfl(de1, srcin, 64);
        if (v < 5) {
          const float dlb = __shfl(accl[u][v + 1][r], lane & 48, 64);
          const float deb = __shfl(acce[u][v + 1][r], lane & 48, 64);
          if (cpos == 15) { dl2 = dlb; de2 = deb; }
        } else if (cpos == 15 && wc == 0) {
          dl2 = hand_d[wr][16 * u + 4 * quad + r][0];
          de2 = hand_d[wr][16 * u + 4 * quad + r][1];
        }
        const int tcol = 96 * wc + 16 * v + cpos;
        const int j = c0 + tcol;
        if (rowok && tcol <= TSTRIDE - 1 && j <= BROWS - 3) {
          const float aa = dl1 - dl2, bb = de1 - de2;
          const float coeff = (float)((aa > 0.f) - (aa < 0.f)) -
                              (float)((bb > 0.f) - (bb < 0.f));
          sum += coeff * (de2 - de1);
        }
      }
    }

  // ---- pass 2: transposed terms (i in cols, pair rows j,j+1), off-diag only ----
  if (!diag) {
#pragma unroll
    for (int u = 0; u < 3; ++u)
#pragma unroll
      for (int v = 0; v < 6; ++v) {
        const int tcol = 96 * wc + 16 * v + cpos;
        const int ii = c0 + tcol;
        const bool colok = (tcol <= TSTRIDE - 1) && (ii <= BROWS - 2);
#pragma unroll
        for (int r = 0; r < 4; ++r) {
          const int trow = 48 * wr + 16 * u + 4 * quad + r;
          const int jj = r0 + trow;
          float dl2, de2;
          if (r < 3) {
            dl2 = accl[u][v][r + 1];
            de2 = acce[u][v][r + 1];
          } else {
            const float dlq = __shfl(accl[u][v][0], (lane + 16) & 63, 64);
            const float deq = __shfl(acce[u][v][0], (lane + 16) & 63, 64);
            const int un = (u < 2) ? u + 1 : u;
            const float dlu = __shfl(accl[un][v][0], cpos, 64);
            const float deu = __shfl(acce[un][v][0], cpos, 64);
            if (quad < 3)    { dl2 = dlq; de2 = deq; }
            else if (u < 2)  { dl2 = dlu; de2 = deu; }
            else             { dl2 = hand_t[wr][tcol][0];   // wr==3 filtered
                               de2 = hand_t[wr][tcol][1]; }
          }
          if (colok && trow <= TSTRIDE - 1 && jj <= BROWS - 3) {
            const float dl1 = accl[u][v][r], de1 = acce[u][v][r];
            const float aa = dl1 - dl2, bb = de1 - de2;
            const float coeff = (float)((aa > 0.f) - (aa < 0.f)) -
                                (float)((bb > 0.f) - (bb < 0.f));
            sum += coeff * (de2 - de1);
          }
        }
      }
  }

  // ---- reduce + atomic ----
#pragma unroll
  for (int o = 32; o; o >>= 1) sum += __shfl_down(sum, o, 64);
  if (lane == 0) sred[wid] = sum;
  __syncthreads();
  if (tid == 0) {
    const float scale = 1.0f / ((float)(BROWS - 1) * (float)(BROWS - 2));
    float t = 0.f;
#pragma unroll
    for (int w = 0; w < 8; ++w) t += sred[w];
    atomicAdd(out, t * scale);
  }
}

// ===========================================================================
extern "C" void kernel_launch(void* const* d_in, const int* in_sizes, int n_in,
                              void* d_out, int out_size, void* d_ws,
                              size_t ws_size, hipStream_t stream) {
  const float* low = (const float*)d_in[0];
  const float* emb = (const float*)d_in[1];
  float* out = (float*)d_out;

  // ws: Yq (2*4096*512 fp8 = 4 MB) then s_l, r_l, s_e, r_e (4096 f32 each)
  unsigned char* Yq = (unsigned char*)d_ws;
  float* s_l = (float*)(Yq + 2 * (size_t)BROWS * DIM);
  float* r_l = s_l + BROWS;
  float* s_e = r_l + BROWS;
  float* r_e = s_e + BROWS;

  prep4_kernel<<<2 * BROWS / 4, 256, 0, stream>>>(low, emb, Yq, s_l, r_l, s_e, r_e, out);
  fused_sym_kernel<<<NT * (NT + 1) / 2, 512, 0, stream>>>(Yq, s_l, r_l, s_e, r_e, out);
}